// Round 10
// baseline (51.760 us; speedup 1.0000x reference)
//
#include <hip/hip_runtime.h>

#define MARGIN 0.15f
#define EPS 1e-8f
#define DD 256           // feature dim (fixed: samples are [512, 256] f32)
#define NN 512           // rows
#define AMAX 4           // anchor sub-batch per block (slice span <= 4 for bench data)
#define NBLK 256         // triplet slices = worker blocks
#define THR 512          // threads per worker block (8 waves)

// ---------------------------------------------------------------------------
// Dispatch 1: fully fused worker. Block b owns triplet slice
// [b*T/NBLK, (b+1)*T/NBLK) (contiguous, no search). ai is sorted, so the
// slice's anchors span [alo, ahi], typ. <= 4 (sub-batch loop if wider).
// Phase A: compute raw dots of the <=4 anchor rows against ALL 512 rows plus
//   all row norms, into LDS. Layout: 8 lanes per row (64 rows per pass, 8
//   passes). Each instruction reads 8 consecutive float4 per 8-lane group —
//   perfectly coalesced L2 streams, anchors via LDS same-address broadcast.
//   3-step shuffle finish per row. No cross-wave deps, 8 waves/CU.
// Phase B: hinge for the slice straight from LDS:
//   v = g[a][n]/max(|a||n|,EPS) - g[a][p]/max(|a||p|,EPS) + margin, relu'd
//   (identical formula to rounds 1-9, absmax 0.0).
// One plain partial[b] store. No atomics, no G in global memory.
// ---------------------------------------------------------------------------
__global__ __launch_bounds__(THR) void fused_rows(
    const float* __restrict__ X,
    const int* __restrict__ ai, const int* __restrict__ pi,
    const int* __restrict__ ni,
    float* __restrict__ partial, int T) {

    __shared__ float As[AMAX * DD];   // 4 KB anchor rows
    __shared__ float g[AMAX][NN];     // 8 KB raw dots
    __shared__ float rn[NN];          // 2 KB row norms
    __shared__ float red[8];

    int t = threadIdx.x;
    int b = blockIdx.x;
    int t0 = (int)((long long)b * T / NBLK);
    int t1 = (int)((long long)(b + 1) * T / NBLK);
    if (t0 >= t1) { if (t == 0) partial[b] = 0.f; return; }

    int alo = ai[t0];
    int ahi = ai[t1 - 1];

    const float4* X4 = (const float4*)X;
    float4* As4 = (float4*)As;

    int grp = t >> 3;                 // 0..63: row group
    int s   = t & 7;                  // 0..7:  slice lane within row
    float sum = 0.f;

    for (int ab = alo; ab <= ahi; ab += AMAX) {
        // stage up to 4 anchor rows (coalesced; clamp unused)
        if (t < AMAX * 64) {
            int i = t >> 6, k = t & 63;
            int ar = ab + i; if (ar >= NN) ar = NN - 1;
            As4[t] = X4[ar * 64 + k];
        }
        __syncthreads();

        // phase A: 8 passes x 64 rows; 8 lanes per row
        for (int pass = 0; pass < 8; ++pass) {
            int j = pass * 64 + grp;
            const float4* xr = X4 + (size_t)j * 64;
            float dp0 = 0.f, dp1 = 0.f, dp2 = 0.f, dp3 = 0.f, ss = 0.f;
#pragma unroll
            for (int k = 0; k < 8; ++k) {
                int idx = k * 8 + s;
                float4 x  = xr[idx];
                float4 a0 = As4[idx];
                float4 a1 = As4[64 + idx];
                float4 a2 = As4[128 + idx];
                float4 a3 = As4[192 + idx];
                dp0 += a0.x * x.x + a0.y * x.y + a0.z * x.z + a0.w * x.w;
                dp1 += a1.x * x.x + a1.y * x.y + a1.z * x.z + a1.w * x.w;
                dp2 += a2.x * x.x + a2.y * x.y + a2.z * x.z + a2.w * x.w;
                dp3 += a3.x * x.x + a3.y * x.y + a3.z * x.z + a3.w * x.w;
                ss  += x.x * x.x + x.y * x.y + x.z * x.z + x.w * x.w;
            }
#pragma unroll
            for (int o = 1; o < 8; o <<= 1) {
                dp0 += __shfl_xor(dp0, o);
                dp1 += __shfl_xor(dp1, o);
                dp2 += __shfl_xor(dp2, o);
                dp3 += __shfl_xor(dp3, o);
                ss  += __shfl_xor(ss, o);
            }
            if (s == 0) {
                g[0][j] = dp0; g[1][j] = dp1; g[2][j] = dp2; g[3][j] = dp3;
                rn[j] = sqrtf(ss);
            }
        }
        __syncthreads();

        // phase B: hinge for slice triplets with anchor in [ab, ab+AMAX)
        int hi2 = ab + AMAX;
        for (int k = t0 + t; k < t1; k += THR) {
            int a = ai[k];
            if (a < ab || a >= hi2) continue;
            int p = pi[k], n = ni[k];
            float rna = rn[a];
            float vn = g[a - ab][n] / fmaxf(rna * rn[n], EPS);
            float vp = g[a - ab][p] / fmaxf(rna * rn[p], EPS);
            float v = vn - vp + MARGIN;
            sum += v > 0.f ? v : 0.f;
        }
        __syncthreads();              // LDS reused if more sub-batches
    }

    // deterministic block reduce (8 waves)
#pragma unroll
    for (int o = 32; o; o >>= 1) sum += __shfl_xor(sum, o);
    int wid = t >> 6;
    if ((t & 63) == 0) red[wid] = sum;
    __syncthreads();
    if (t == 0) {
        float r = 0.f;
#pragma unroll
        for (int i = 0; i < 8; ++i) r += red[i];
        partial[b] = r;
    }
}

// ---------------------------------------------------------------------------
// Dispatch 2: fixed-order final reduce over block partials, scale by 1/T.
// ---------------------------------------------------------------------------
__global__ __launch_bounds__(256) void reduce_partials(const float* __restrict__ partial,
                                                       int nb, float invT,
                                                       float* __restrict__ out) {
    float s = 0.f;
    for (int i = threadIdx.x; i < nb; i += 256) s += partial[i];
#pragma unroll
    for (int off = 32; off; off >>= 1) s += __shfl_xor(s, off);
    __shared__ float red[4];
    int wid = threadIdx.x >> 6;
    if ((threadIdx.x & 63) == 0) red[wid] = s;
    __syncthreads();
    if (threadIdx.x == 0) out[0] = (red[0] + red[1] + red[2] + red[3]) * invT;
}

// ---------------------------------------------------------------------------
// Fallback kernels (odd shapes / tiny ws): norms + direct dots + reduce.
// ---------------------------------------------------------------------------
__global__ __launch_bounds__(256) void norm_rows(const float* __restrict__ X,
                                                 float* __restrict__ rnorm, int N) {
    int row = blockIdx.x * 4 + (threadIdx.x >> 6);
    if (row >= N) return;
    int lane = threadIdx.x & 63;
    float4 v = ((const float4*)(X + (size_t)row * DD))[lane];
    float ss = v.x * v.x + v.y * v.y + v.z * v.z + v.w * v.w;
#pragma unroll
    for (int off = 32; off; off >>= 1) ss += __shfl_xor(ss, off);
    if (lane == 0) rnorm[row] = sqrtf(ss);
}

__global__ __launch_bounds__(256) void triplet_direct(const float* __restrict__ X,
                                                      const float* __restrict__ rnorm,
                                                      const int* __restrict__ ai,
                                                      const int* __restrict__ pi,
                                                      const int* __restrict__ ni,
                                                      float* __restrict__ partial,
                                                      int T, int N) {
    float sum = 0.f;
    for (int t = blockIdx.x * blockDim.x + threadIdx.x; t < T;
         t += gridDim.x * blockDim.x) {
        int a = ai[t], p = pi[t], n = ni[t];
        const float4* xa = (const float4*)(X + (size_t)a * DD);
        const float4* xp = (const float4*)(X + (size_t)p * DD);
        const float4* xn = (const float4*)(X + (size_t)n * DD);
        float dp = 0.f, dn = 0.f;
#pragma unroll 4
        for (int k = 0; k < DD / 4; ++k) {
            float4 av = xa[k], pv = xp[k], nv = xn[k];
            dp += av.x * pv.x + av.y * pv.y + av.z * pv.z + av.w * pv.w;
            dn += av.x * nv.x + av.y * nv.y + av.z * nv.z + av.w * nv.w;
        }
        float na = rnorm[a];
        float v = dn / fmaxf(na * rnorm[n], EPS) - dp / fmaxf(na * rnorm[p], EPS) + MARGIN;
        sum += v > 0.f ? v : 0.f;
    }
#pragma unroll
    for (int off = 32; off; off >>= 1) sum += __shfl_xor(sum, off);
    __shared__ float red[4];
    int wid = threadIdx.x >> 6;
    if ((threadIdx.x & 63) == 0) red[wid] = sum;
    __syncthreads();
    if (threadIdx.x == 0) partial[blockIdx.x] = red[0] + red[1] + red[2] + red[3];
}

extern "C" void kernel_launch(void* const* d_in, const int* in_sizes, int n_in,
                              void* d_out, int out_size, void* d_ws, size_t ws_size,
                              hipStream_t stream) {
    const float* X  = (const float*)d_in[0];   // samples [N, D] f32
    const int*   ai = (const int*)d_in[2];     // anchor_idx [T] (sorted)
    const int*   pi = (const int*)d_in[3];     // pos_idx [T]
    const int*   ni = (const int*)d_in[4];     // neg_idx [T]
    float* out = (float*)d_out;

    int N = in_sizes[1];                       // 512
    int T = in_sizes[2];

    if (N == NN && in_sizes[0] == NN * DD && T > 0 &&
        ws_size >= (size_t)NBLK * sizeof(float)) {
        // Path A: fused worker (gram-rows + gather, zero cross-block sync)
        //         + 1-block reduce.  2 dispatches, no atomics.
        float* partial = (float*)d_ws;
        fused_rows<<<NBLK, THR, 0, stream>>>(X, ai, pi, ni, partial, T);
        reduce_partials<<<1, 256, 0, stream>>>(partial, NBLK, 1.0f / (float)T, out);
    } else {
        // Path B: norms + direct per-triplet dots + reduce (3 dispatches)
        float* rnorm   = (float*)d_ws;
        float* partial = rnorm + N;
        int NB = (T + 255) / 256;
        if (NB > 2048) NB = 2048;
        if (NB < 1) NB = 1;
        norm_rows<<<(N + 3) / 4, 256, 0, stream>>>(X, rnorm, N);
        triplet_direct<<<NB, 256, 0, stream>>>(X, rnorm, ai, pi, ni, partial, T, N);
        reduce_partials<<<1, 256, 0, stream>>>(partial, NB, 1.0f / (float)T, out);
    }
}

// Round 11
// 15.436 us; speedup vs baseline: 3.3533x; 3.3533x over previous
//
#include <hip/hip_runtime.h>

#define MARGIN 0.15f
#define EPS 1e-8f
#define D 256            // feature dim (fixed: samples are [512, 256] f32)
#define GT 32            // gram tile
#define LDP (D + 4)      // padded LDS row stride (floats), 16B-aligned rows
#define NWB 512          // worker blocks in kernel 2 (2 waves/SIMD for gather TLP)
#define NGB 256          // gram blocks (16x16)
#define SLOT_U32 32      // u32 stride per slot line (128 B)
#define SENT 0xFFFFFFFFu // NaN bit pattern; worker partials are finite >= 0

// ---------------------------------------------------------------------------
// Kernel 1: fused row-norm + Gram tile (body proven r2-r9, absmax 0.0).
// G[a,b] = dot(X_a,X_b)/max(|a||b|,EPS) — exactly the reference cosine form.
// Each of the 256 blocks plain-stores sentinels into TWO slot lines (id,
// id+256) for kernel 2's 512 workers (cross-dispatch store->atomic-read
// visibility proven r5/r9).
// ---------------------------------------------------------------------------
__global__ __launch_bounds__(256) void norm_gram(const float* __restrict__ X,
                                                 float* __restrict__ G,
                                                 unsigned int* __restrict__ slots,
                                                 int N) {
    __shared__ float As[GT][LDP];
    __shared__ float Bs[GT][LDP];
    __shared__ float na[GT], nb[GT];
    int t = threadIdx.x;
    if (t == 0) {
        int id = blockIdx.y * gridDim.x + blockIdx.x;   // 0..255
        slots[id * SLOT_U32] = SENT;
        slots[(id + NGB) * SLOT_U32] = SENT;
    }

    const float4* A4 = (const float4*)(X + (size_t)blockIdx.y * GT * D);
    const float4* B4 = (const float4*)(X + (size_t)blockIdx.x * GT * D);
#pragma unroll
    for (int i = 0; i < 8; ++i) {
        int f = t + i * 256;          // 0..2047 float4s per 32x256 tile
        int r = f >> 6, c = f & 63;
        *(float4*)&As[r][c * 4] = A4[f];
        *(float4*)&Bs[r][c * 4] = B4[f];
    }
    __syncthreads();

    // Row norms from LDS: 8 adjacent lanes per row.
    {
        int row = t >> 3, sub = t & 7;
        float ssA = 0.f, ssB = 0.f;
#pragma unroll
        for (int j = 0; j < 8; ++j) {
            float4 a = *(const float4*)&As[row][(sub * 8 + j) * 4];
            ssA += a.x * a.x + a.y * a.y + a.z * a.z + a.w * a.w;
            float4 b = *(const float4*)&Bs[row][(sub * 8 + j) * 4];
            ssB += b.x * b.x + b.y * b.y + b.z * b.z + b.w * b.w;
        }
#pragma unroll
        for (int off = 1; off < 8; off <<= 1) {
            ssA += __shfl_xor(ssA, off);
            ssB += __shfl_xor(ssB, off);
        }
        if (sub == 0) { na[row] = sqrtf(ssA); nb[row] = sqrtf(ssB); }
    }
    __syncthreads();

    int tx = t & 15, ty = t >> 4;
    int r0 = ty * 2, c0 = tx * 2;
    float acc00 = 0.f, acc01 = 0.f, acc10 = 0.f, acc11 = 0.f;
#pragma unroll 4
    for (int k = 0; k < D; k += 4) {
        float4 a0 = *(const float4*)&As[r0][k];
        float4 a1 = *(const float4*)&As[r0 + 1][k];
        float4 b0 = *(const float4*)&Bs[c0][k];
        float4 b1 = *(const float4*)&Bs[c0 + 1][k];
        acc00 += a0.x * b0.x + a0.y * b0.y + a0.z * b0.z + a0.w * b0.w;
        acc01 += a0.x * b1.x + a0.y * b1.y + a0.z * b1.z + a0.w * b1.w;
        acc10 += a1.x * b0.x + a1.y * b0.y + a1.z * b0.z + a1.w * b0.w;
        acc11 += a1.x * b1.x + a1.y * b1.y + a1.z * b1.z + a1.w * b1.w;
    }
    float nA0 = na[r0], nA1 = na[r0 + 1], nB0 = nb[c0], nB1 = nb[c0 + 1];
    size_t orow = (size_t)(blockIdx.y * GT + r0) * N + blockIdx.x * GT + c0;
    float2 o0 = {acc00 / fmaxf(nA0 * nB0, EPS), acc01 / fmaxf(nA0 * nB1, EPS)};
    float2 o1 = {acc10 / fmaxf(nA1 * nB0, EPS), acc11 / fmaxf(nA1 * nB1, EPS)};
    *(float2*)&G[orow]     = o0;
    *(float2*)&G[orow + N] = o1;
}

// ---------------------------------------------------------------------------
// Kernel 2: triplet hinge gather (r4/r9-proven int2 form, now 512 blocks =
// 2 waves/SIMD for latency hiding) + sentinel-slot finisher.  Each block
// publishes its fixed-order partial with ONE atomicExch to its own 128B line
// (512 parallel lines, no serialization).  Block 0: lane i spin-reads slots
// i and i+256 (atomic loads, distinct lines, s_sleep backoff) until
// non-sentinel, then fixed-order tree -> out.  Deterministic throughout.
// d_pos - d_neg + m = G[a,n] - G[a,p] + m.
// ---------------------------------------------------------------------------
__global__ __launch_bounds__(256) void triplet_finish(
    const float* __restrict__ G, const int* __restrict__ ai,
    const int* __restrict__ pi, const int* __restrict__ ni,
    unsigned int* __restrict__ slots, int T, int N, float invT,
    float* __restrict__ out) {
    const int2* ai2 = (const int2*)ai;
    const int2* pi2 = (const int2*)pi;
    const int2* ni2 = (const int2*)ni;
    int half = T >> 1;
    float sum = 0.f;
    int t = threadIdx.x;
    int tid = blockIdx.x * 256 + t;
    int stride = NWB * 256;
    for (int k = tid; k < half; k += stride) {
        int2 a = ai2[k], p = pi2[k], n = ni2[k];
        float v0 = G[a.x * N + n.x] - G[a.x * N + p.x] + MARGIN;
        float v1 = G[a.y * N + n.y] - G[a.y * N + p.y] + MARGIN;
        sum += (v0 > 0.f ? v0 : 0.f) + (v1 > 0.f ? v1 : 0.f);
    }
    if (tid == 0 && (T & 1)) {
        int k = T - 1;
        float v = G[ai[k] * N + ni[k]] - G[ai[k] * N + pi[k]] + MARGIN;
        sum += v > 0.f ? v : 0.f;
    }
#pragma unroll
    for (int off = 32; off; off >>= 1) sum += __shfl_xor(sum, off);
    __shared__ float red[4];
    int wid = t >> 6;
    if ((t & 63) == 0) red[wid] = sum;
    __syncthreads();
    if (t == 0) {
        float bsum = red[0] + red[1] + red[2] + red[3];   // finite, >= 0
        atomicExch(&slots[blockIdx.x * SLOT_U32], __float_as_uint(bsum));
    }
    // ---- finisher: block 0, lane i waits on slots i and i+256 ----
    if (blockIdx.x == 0) {
        unsigned int u0 = atomicAdd(&slots[t * SLOT_U32], 0u);
        while (u0 == SENT) {
            __builtin_amdgcn_s_sleep(2);
            u0 = atomicAdd(&slots[t * SLOT_U32], 0u);
        }
        unsigned int u1 = atomicAdd(&slots[(t + 256) * SLOT_U32], 0u);
        while (u1 == SENT) {
            __builtin_amdgcn_s_sleep(2);
            u1 = atomicAdd(&slots[(t + 256) * SLOT_U32], 0u);
        }
        float s = __uint_as_float(u0) + __uint_as_float(u1);
#pragma unroll
        for (int off = 32; off; off >>= 1) s += __shfl_xor(s, off);
        if ((t & 63) == 0) red[wid] = s;
        __syncthreads();
        if (t == 0) out[0] = (red[0] + red[1] + red[2] + red[3]) * invT;
    }
}

// ---------------------------------------------------------------------------
// Fallback kernels (odd shapes / tiny ws): norms + direct dots + reduce.
// ---------------------------------------------------------------------------
__global__ __launch_bounds__(256) void norm_rows(const float* __restrict__ X,
                                                 float* __restrict__ rnorm, int N) {
    int row = blockIdx.x * 4 + (threadIdx.x >> 6);
    if (row >= N) return;
    int lane = threadIdx.x & 63;
    float4 v = ((const float4*)(X + (size_t)row * D))[lane];
    float ss = v.x * v.x + v.y * v.y + v.z * v.z + v.w * v.w;
#pragma unroll
    for (int off = 32; off; off >>= 1) ss += __shfl_xor(ss, off);
    if (lane == 0) rnorm[row] = sqrtf(ss);
}

__global__ __launch_bounds__(256) void triplet_direct(const float* __restrict__ X,
                                                      const float* __restrict__ rnorm,
                                                      const int* __restrict__ ai,
                                                      const int* __restrict__ pi,
                                                      const int* __restrict__ ni,
                                                      float* __restrict__ partial,
                                                      int T, int N) {
    float sum = 0.f;
    for (int t = blockIdx.x * blockDim.x + threadIdx.x; t < T;
         t += gridDim.x * blockDim.x) {
        int a = ai[t], p = pi[t], n = ni[t];
        const float4* xa = (const float4*)(X + (size_t)a * D);
        const float4* xp = (const float4*)(X + (size_t)p * D);
        const float4* xn = (const float4*)(X + (size_t)n * D);
        float dp = 0.f, dn = 0.f;
#pragma unroll 4
        for (int k = 0; k < D / 4; ++k) {
            float4 av = xa[k], pv = xp[k], nv = xn[k];
            dp += av.x * pv.x + av.y * pv.y + av.z * pv.z + av.w * pv.w;
            dn += av.x * nv.x + av.y * nv.y + av.z * nv.z + av.w * nv.w;
        }
        float na = rnorm[a];
        float v = dn / fmaxf(na * rnorm[n], EPS) - dp / fmaxf(na * rnorm[p], EPS) + MARGIN;
        sum += v > 0.f ? v : 0.f;
    }
#pragma unroll
    for (int off = 32; off; off >>= 1) sum += __shfl_xor(sum, off);
    __shared__ float red[4];
    int wid = threadIdx.x >> 6;
    if ((threadIdx.x & 63) == 0) red[wid] = sum;
    __syncthreads();
    if (threadIdx.x == 0) partial[blockIdx.x] = red[0] + red[1] + red[2] + red[3];
}

__global__ __launch_bounds__(256) void reduce_partials(const float* __restrict__ partial,
                                                       int nb, float invT,
                                                       float* __restrict__ out) {
    float s = 0.f;
    for (int i = threadIdx.x; i < nb; i += 256) s += partial[i];
#pragma unroll
    for (int off = 32; off; off >>= 1) s += __shfl_xor(s, off);
    __shared__ float red[4];
    int wid = threadIdx.x >> 6;
    if ((threadIdx.x & 63) == 0) red[wid] = s;
    __syncthreads();
    if (threadIdx.x == 0) out[0] = (red[0] + red[1] + red[2] + red[3]) * invT;
}

extern "C" void kernel_launch(void* const* d_in, const int* in_sizes, int n_in,
                              void* d_out, int out_size, void* d_ws, size_t ws_size,
                              hipStream_t stream) {
    const float* X  = (const float*)d_in[0];   // samples [N, D] f32
    const int*   ai = (const int*)d_in[2];     // anchor_idx [T]
    const int*   pi = (const int*)d_in[3];     // pos_idx [T]
    const int*   ni = (const int*)d_in[4];     // neg_idx [T]
    float* out = (float*)d_out;

    int N = in_sizes[1];                       // 512
    int T = in_sizes[2];

    size_t gB    = (size_t)N * N * sizeof(float);
    size_t slotB = (size_t)NWB * SLOT_U32 * sizeof(unsigned int);

    if (ws_size >= gB + slotB && (N % GT) == 0 && (N / GT) * (N / GT) == NGB &&
        T > 0) {
        // Path A: norm+gram (+sentinel init x2) -> gather(512 blk) + finisher
        float*        G     = (float*)d_ws;
        unsigned int* slots = (unsigned int*)((char*)d_ws + gB);
        dim3 gg(N / GT, N / GT);               // 16x16 = 256 = NGB
        norm_gram<<<gg, 256, 0, stream>>>(X, G, slots, N);
        triplet_finish<<<NWB, 256, 0, stream>>>(G, ai, pi, ni, slots,
                                                T, N, 1.0f / (float)T, out);
    } else {
        // Path B: norms + direct per-triplet dots + reduce (3 dispatches)
        float* rnorm   = (float*)d_ws;
        float* partial = rnorm + N;
        int NB = (T + 255) / 256;
        if (NB > 2048) NB = 2048;
        if (NB < 1) NB = 1;
        norm_rows<<<(N + 3) / 4, 256, 0, stream>>>(X, rnorm, N);
        triplet_direct<<<NB, 256, 0, stream>>>(X, rnorm, ai, pi, ni, partial, T, N);
        reduce_partials<<<1, 256, 0, stream>>>(partial, NB, 1.0f / (float)T, out);
    }
}

// Round 12
// 13.220 us; speedup vs baseline: 3.9153x; 1.1676x over previous
//
#include <hip/hip_runtime.h>

#define MARGIN 0.15f
#define EPS 1e-8f
#define D 256            // feature dim (fixed: samples are [512, 256] f32)
#define GT 32            // gram tile
#define KP 264           // padded bf16 row stride (256 + 8): frag reads 2-way-free
#define NWB 512          // worker blocks in gather (2 waves/SIMD, r11-proven)
#define NGB 256          // gram blocks (16x16)
#define SLOT_U32 32      // u32 stride per slot line (128 B)
#define SENT 0xFFFFFFFFu // sentinel; worker partials are finite >= 0

using short8  = __attribute__((ext_vector_type(8))) short;
using float4v = __attribute__((ext_vector_type(4))) float;

__device__ __forceinline__ unsigned short bf_rne(float x) {
    unsigned int u = __float_as_uint(x);
    unsigned int r = (u + 0x7FFFu + ((u >> 16) & 1u)) >> 16;   // round-nearest-even
    return (unsigned short)r;
}

// ---------------------------------------------------------------------------
// Kernel 1: bf16-MFMA fused row-norm + Gram tile.
// G[a,b] = dot(bf16(X_a), bf16(X_b)) / max(|bf16(X_a)||bf16(X_b)|, EPS)
// — the reference cosine formula evaluated on bf16-rounded rows (self-
// consistent numerator/denominator; f32 MFMA accumulate).
// 32x32 tile per 256-thread block; X staged f32->bf16 into padded LDS;
// norms from the staged bf16 (8 lanes/row shuffle reduce); each of the 4
// waves computes one 16x16 quadrant via 8x mfma_f32_16x16x32_bf16.
// Frag layout (guide §3): A/B non-K dim = lane&15, k = (lane>>4)*8 + reg;
// C/D col = lane&15, row = (lane>>4)*4 + reg  [m89-verified].
// Each block also plain-stores sentinels into slot lines id and id+256
// (cross-dispatch store->atomic-read visibility proven r5/r9/r11).
// ---------------------------------------------------------------------------
__global__ __launch_bounds__(256) void norm_gram_mfma(
    const float* __restrict__ X, float* __restrict__ G,
    unsigned int* __restrict__ slots, int N) {

    __shared__ unsigned short Ab[GT * KP];
    __shared__ unsigned short Bb[GT * KP];
    __shared__ float na[GT], nb[GT];

    int t = threadIdx.x;
    if (t == 0) {
        int id = blockIdx.y * gridDim.x + blockIdx.x;   // 0..255
        slots[id * SLOT_U32] = SENT;
        slots[(id + NGB) * SLOT_U32] = SENT;
    }

    int R = blockIdx.y * GT;
    int C = blockIdx.x * GT;
    const float4* A4 = (const float4*)(X + (size_t)R * D);
    const float4* B4 = (const float4*)(X + (size_t)C * D);

    // stage f32 -> bf16 LDS (32 rows x 256, padded to 264)
#pragma unroll
    for (int i = 0; i < 8; ++i) {
        int f = t + i * 256;          // 0..2047 float4s per 32x256 tile
        int r = f >> 6, c4 = f & 63;
        float4 a = A4[f];
        ushort4 ha = {bf_rne(a.x), bf_rne(a.y), bf_rne(a.z), bf_rne(a.w)};
        *(ushort4*)&Ab[r * KP + c4 * 4] = ha;
        float4 b = B4[f];
        ushort4 hb = {bf_rne(b.x), bf_rne(b.y), bf_rne(b.z), bf_rne(b.w)};
        *(ushort4*)&Bb[r * KP + c4 * 4] = hb;
    }
    __syncthreads();

    // row norms from staged bf16: 8 lanes per row, 4x16B each
    {
        int row = t >> 3, sub = t & 7;
        float ssA = 0.f, ssB = 0.f;
#pragma unroll
        for (int j = 0; j < 4; ++j) {
            uint4 wa = *(const uint4*)&Ab[row * KP + sub * 32 + j * 8];
            uint4 wb = *(const uint4*)&Bb[row * KP + sub * 32 + j * 8];
            const unsigned int va[4] = {wa.x, wa.y, wa.z, wa.w};
            const unsigned int vb[4] = {wb.x, wb.y, wb.z, wb.w};
#pragma unroll
            for (int q = 0; q < 4; ++q) {
                float a0 = __uint_as_float(va[q] << 16);
                float a1 = __uint_as_float(va[q] & 0xFFFF0000u);
                ssA += a0 * a0 + a1 * a1;
                float b0 = __uint_as_float(vb[q] << 16);
                float b1 = __uint_as_float(vb[q] & 0xFFFF0000u);
                ssB += b0 * b0 + b1 * b1;
            }
        }
#pragma unroll
        for (int off = 1; off < 8; off <<= 1) {
            ssA += __shfl_xor(ssA, off);
            ssB += __shfl_xor(ssB, off);
        }
        if (sub == 0) { na[row] = sqrtf(ssA); nb[row] = sqrtf(ssB); }
    }
    __syncthreads();

    // MFMA: wave w -> quadrant (wr, wc); 8 k-steps of 16x16x32
    int w = t >> 6, lane = t & 63;
    int wr = w >> 1, wc = w & 1;
    int ar = wr * 16 + (lane & 15);
    int br = wc * 16 + (lane & 15);
    int ko = (lane >> 4) * 8;
    float4v acc = {0.f, 0.f, 0.f, 0.f};
#pragma unroll
    for (int ks = 0; ks < 8; ++ks) {
        short8 af = *(const short8*)&Ab[ar * KP + ks * 32 + ko];
        short8 bf = *(const short8*)&Bb[br * KP + ks * 32 + ko];
        acc = __builtin_amdgcn_mfma_f32_16x16x32_bf16(af, bf, acc, 0, 0, 0);
    }
#pragma unroll
    for (int reg = 0; reg < 4; ++reg) {
        int gr = wr * 16 + (lane >> 4) * 4 + reg;   // row within 32x32 tile
        int gc = wc * 16 + (lane & 15);             // col within 32x32 tile
        float o = acc[reg] / fmaxf(na[gr] * nb[gc], EPS);
        G[(size_t)(R + gr) * N + (C + gc)] = o;
    }
}

// ---------------------------------------------------------------------------
// Kernel 2 (verbatim r11, proven): triplet hinge gather (int2, 512 blocks)
// + sentinel-slot finisher.  d_pos - d_neg + m = G[a,n] - G[a,p] + m.
// ---------------------------------------------------------------------------
__global__ __launch_bounds__(256) void triplet_finish(
    const float* __restrict__ G, const int* __restrict__ ai,
    const int* __restrict__ pi, const int* __restrict__ ni,
    unsigned int* __restrict__ slots, int T, int N, float invT,
    float* __restrict__ out) {
    const int2* ai2 = (const int2*)ai;
    const int2* pi2 = (const int2*)pi;
    const int2* ni2 = (const int2*)ni;
    int half = T >> 1;
    float sum = 0.f;
    int t = threadIdx.x;
    int tid = blockIdx.x * 256 + t;
    int stride = NWB * 256;
    for (int k = tid; k < half; k += stride) {
        int2 a = ai2[k], p = pi2[k], n = ni2[k];
        float v0 = G[a.x * N + n.x] - G[a.x * N + p.x] + MARGIN;
        float v1 = G[a.y * N + n.y] - G[a.y * N + p.y] + MARGIN;
        sum += (v0 > 0.f ? v0 : 0.f) + (v1 > 0.f ? v1 : 0.f);
    }
    if (tid == 0 && (T & 1)) {
        int k = T - 1;
        float v = G[ai[k] * N + ni[k]] - G[ai[k] * N + pi[k]] + MARGIN;
        sum += v > 0.f ? v : 0.f;
    }
#pragma unroll
    for (int off = 32; off; off >>= 1) sum += __shfl_xor(sum, off);
    __shared__ float red[4];
    int wid = t >> 6;
    if ((t & 63) == 0) red[wid] = sum;
    __syncthreads();
    if (t == 0) {
        float bsum = red[0] + red[1] + red[2] + red[3];   // finite, >= 0
        atomicExch(&slots[blockIdx.x * SLOT_U32], __float_as_uint(bsum));
    }
    if (blockIdx.x == 0) {
        unsigned int u0 = atomicAdd(&slots[t * SLOT_U32], 0u);
        while (u0 == SENT) {
            __builtin_amdgcn_s_sleep(2);
            u0 = atomicAdd(&slots[t * SLOT_U32], 0u);
        }
        unsigned int u1 = atomicAdd(&slots[(t + 256) * SLOT_U32], 0u);
        while (u1 == SENT) {
            __builtin_amdgcn_s_sleep(2);
            u1 = atomicAdd(&slots[(t + 256) * SLOT_U32], 0u);
        }
        float s = __uint_as_float(u0) + __uint_as_float(u1);
#pragma unroll
        for (int off = 32; off; off >>= 1) s += __shfl_xor(s, off);
        if ((t & 63) == 0) red[wid] = s;
        __syncthreads();
        if (t == 0) out[0] = (red[0] + red[1] + red[2] + red[3]) * invT;
    }
}

// ---------------------------------------------------------------------------
// Fallback kernels (odd shapes / tiny ws): norms + direct dots + reduce (f32).
// ---------------------------------------------------------------------------
__global__ __launch_bounds__(256) void norm_rows(const float* __restrict__ X,
                                                 float* __restrict__ rnorm, int N) {
    int row = blockIdx.x * 4 + (threadIdx.x >> 6);
    if (row >= N) return;
    int lane = threadIdx.x & 63;
    float4 v = ((const float4*)(X + (size_t)row * D))[lane];
    float ss = v.x * v.x + v.y * v.y + v.z * v.z + v.w * v.w;
#pragma unroll
    for (int off = 32; off; off >>= 1) ss += __shfl_xor(ss, off);
    if (lane == 0) rnorm[row] = sqrtf(ss);
}

__global__ __launch_bounds__(256) void triplet_direct(const float* __restrict__ X,
                                                      const float* __restrict__ rnorm,
                                                      const int* __restrict__ ai,
                                                      const int* __restrict__ pi,
                                                      const int* __restrict__ ni,
                                                      float* __restrict__ partial,
                                                      int T, int N) {
    float sum = 0.f;
    for (int t = blockIdx.x * blockDim.x + threadIdx.x; t < T;
         t += gridDim.x * blockDim.x) {
        int a = ai[t], p = pi[t], n = ni[t];
        const float4* xa = (const float4*)(X + (size_t)a * D);
        const float4* xp = (const float4*)(X + (size_t)p * D);
        const float4* xn = (const float4*)(X + (size_t)n * D);
        float dp = 0.f, dn = 0.f;
#pragma unroll 4
        for (int k = 0; k < D / 4; ++k) {
            float4 av = xa[k], pv = xp[k], nv = xn[k];
            dp += av.x * pv.x + av.y * pv.y + av.z * pv.z + av.w * pv.w;
            dn += av.x * nv.x + av.y * nv.y + av.z * nv.z + av.w * nv.w;
        }
        float na = rnorm[a];
        float v = dn / fmaxf(na * rnorm[n], EPS) - dp / fmaxf(na * rnorm[p], EPS) + MARGIN;
        sum += v > 0.f ? v : 0.f;
    }
#pragma unroll
    for (int off = 32; off; off >>= 1) sum += __shfl_xor(sum, off);
    __shared__ float red[4];
    int wid = threadIdx.x >> 6;
    if ((threadIdx.x & 63) == 0) red[wid] = sum;
    __syncthreads();
    if (threadIdx.x == 0) partial[blockIdx.x] = red[0] + red[1] + red[2] + red[3];
}

__global__ __launch_bounds__(256) void reduce_partials(const float* __restrict__ partial,
                                                       int nb, float invT,
                                                       float* __restrict__ out) {
    float s = 0.f;
    for (int i = threadIdx.x; i < nb; i += 256) s += partial[i];
#pragma unroll
    for (int off = 32; off; off >>= 1) s += __shfl_xor(s, off);
    __shared__ float red[4];
    int wid = threadIdx.x >> 6;
    if ((threadIdx.x & 63) == 0) red[wid] = s;
    __syncthreads();
    if (threadIdx.x == 0) out[0] = (red[0] + red[1] + red[2] + red[3]) * invT;
}

extern "C" void kernel_launch(void* const* d_in, const int* in_sizes, int n_in,
                              void* d_out, int out_size, void* d_ws, size_t ws_size,
                              hipStream_t stream) {
    const float* X  = (const float*)d_in[0];   // samples [N, D] f32
    const int*   ai = (const int*)d_in[2];     // anchor_idx [T]
    const int*   pi = (const int*)d_in[3];     // pos_idx [T]
    const int*   ni = (const int*)d_in[4];     // neg_idx [T]
    float* out = (float*)d_out;

    int N = in_sizes[1];                       // 512
    int T = in_sizes[2];

    size_t gB    = (size_t)N * N * sizeof(float);
    size_t slotB = (size_t)NWB * SLOT_U32 * sizeof(unsigned int);

    if (ws_size >= gB + slotB && (N % GT) == 0 && (N / GT) * (N / GT) == NGB &&
        T > 0) {
        // Path A: bf16-MFMA norm+gram (+sentinel init) -> gather + finisher
        float*        G     = (float*)d_ws;
        unsigned int* slots = (unsigned int*)((char*)d_ws + gB);
        dim3 gg(N / GT, N / GT);               // 16x16 = 256 = NGB
        norm_gram_mfma<<<gg, 256, 0, stream>>>(X, G, slots, N);
        triplet_finish<<<NWB, 256, 0, stream>>>(G, ai, pi, ni, slots,
                                                T, N, 1.0f / (float)T, out);
    } else {
        // Path B: norms + direct per-triplet dots + reduce (3 dispatches, f32)
        float* rnorm   = (float*)d_ws;
        float* partial = rnorm + N;
        int NB = (T + 255) / 256;
        if (NB > 2048) NB = 2048;
        if (NB < 1) NB = 1;
        norm_rows<<<(N + 3) / 4, 256, 0, stream>>>(X, rnorm, N);
        triplet_direct<<<NB, 256, 0, stream>>>(X, rnorm, ai, pi, ni, partial, T, N);
        reduce_partials<<<1, 256, 0, stream>>>(partial, NB, 1.0f / (float)T, out);
    }
}